// Round 8
// baseline (38.259 us; speedup 1.0000x reference)
//
#include <hip/hip_runtime.h>

// Problem constants (match reference).
#define BB   64
#define NN   900
#define MM   300
#define NC1  92          // NUM_CLASSES + 1
#define MQ   75          // float4 groups per m-row (300/4)

__global__ __launch_bounds__(256) void cost_kernel(
    const float4* __restrict__ bbox_pred,   // [B*N] (cx,cy,w,h)
    const float*  __restrict__ labels_pred, // [B*N*92]
    const float4* __restrict__ bbox_gt,     // [B*M]
    const int4*   __restrict__ labels_gt,   // [B*M/4]
    float4*       __restrict__ out)         // [B*N*MQ]
{
    const int total = BB * NN * MQ;         // 4,320,000
    int idx = blockIdx.x * blockDim.x + threadIdx.x;
    if (idx >= total) return;

    int mq = idx % MQ;
    int bn = idx / MQ;      // b*N + n
    int b  = bn / NN;

    // ---- Issue all independent loads up front ----
    float4 p  = bbox_pred[bn];
    int4   lg = labels_gt[b * MQ + mq];
    float4 g4[4];
#pragma unroll
    for (int j = 0; j < 4; ++j)
        g4[j] = bbox_gt[b * MM + mq * 4 + j];

    const float* lp_row = labels_pred + (size_t)bn * NC1;
    int lbl[4] = { lg.x, lg.y, lg.z, lg.w };
    float cls[4];
#pragma unroll
    for (int j = 0; j < 4; ++j)            // 4 gathers, all same L1-hot row
        cls[j] = lp_row[lbl[j]];

    // ---- p-state ----
    float pux  = p.x - 0.5f * p.z,  puy  = p.y - 0.5f * p.w;
    float pdx1 = p.x + 0.5f * p.z + 1.0f;
    float pdy1 = p.y + 0.5f * p.w + 1.0f;
    float pz1  = p.z + 1.0f,        pw1  = p.w + 1.0f;
    float p_area = pz1 * pw1;

    float res[4];
#pragma unroll
    for (int j = 0; j < 4; ++j) {
        float4 g = g4[j];
        float gux  = g.x - 0.5f * g.z,  guy  = g.y - 0.5f * g.w;
        float gdx1 = g.x + 0.5f * g.z + 1.0f;
        float gdy1 = g.y + 0.5f * g.w + 1.0f;
        float gz1  = g.z + 1.0f,        gw1  = g.w + 1.0f;

        float iwrx = fminf(pdx1, gdx1) - fmaxf(pux, gux);
        float iwry = fminf(pdy1, gdy1) - fmaxf(puy, guy);
        float inter = fmaxf(iwrx, 0.0f) * fmaxf(iwry, 0.0f);

        // bound via sum identity: iw_raw + bw = (pz+1)+(gz+1)
        float bwx = (pz1 + gz1) - iwrx;
        float bwy = (pw1 + gw1) - iwry;
        float barea = bwx * bwy;

        float uni = (p_area + gz1 * gw1) - inter;
        float iou = inter * __builtin_amdgcn_rcpf(uni);
        float tt  = uni   * __builtin_amdgcn_rcpf(barea);   // bg = 1 - tt

        float bbox = fabsf(p.x - g.x) + fabsf(p.y - g.y)
                   + fabsf(p.z - g.z) + fabsf(p.w - g.w);

        res[j] = bbox + (1.0f - cls[j]) - tt - iou;
    }

    out[idx] = make_float4(res[0], res[1], res[2], res[3]);
}

extern "C" void kernel_launch(void* const* d_in, const int* in_sizes, int n_in,
                              void* d_out, int out_size, void* d_ws, size_t ws_size,
                              hipStream_t stream) {
    const float4* bbox_pred   = (const float4*)d_in[0];
    const float*  labels_pred = (const float*) d_in[1];
    const float4* bbox_gt     = (const float4*)d_in[2];
    const int4*   labels_gt   = (const int4*)  d_in[3];
    float4*       out         = (float4*)d_out;

    const int total = BB * NN * MQ;
    const int block = 256;
    const int grid  = (total + block - 1) / block;   // 16875 blocks
    cost_kernel<<<grid, block, 0, stream>>>(bbox_pred, labels_pred, bbox_gt,
                                            labels_gt, out);
}

// Round 9
// 35.498 us; speedup vs baseline: 1.0778x; 1.0778x over previous
//
#include <hip/hip_runtime.h>

// Problem constants (match reference).
#define BB    64
#define NN    900
#define MM    300
#define NC1   92
#define MQ    75               // m-groups of 4
#define KN    2                // n-rows per item
#define NCH   (NN / KN)        // 450
#define TOTAL (BB * NCH * MQ)  // 2,160,000 items
#define ITEMS 8                // items per thread
#define BD    256
#define GRID  1055             // ceil(TOTAL/ITEMS/BD)
#define STRIDE (GRID * BD)     // 270,080

struct Item {
    int bn0, mq, valid;
    int4 lg;
    float4 g0, g1, g2, g3;
    float4 p0, p1;
    float cls[KN][4];
};

__device__ __forceinline__ void load_s1(Item& it, int idx,
    const float4* __restrict__ bbox_pred,
    const float4* __restrict__ bbox_gt,
    const int4*   __restrict__ labels_gt)
{
    it.valid = (idx < TOTAL);
    int i = it.valid ? idx : 0;
    int mq   = i % MQ;
    int rest = i / MQ;
    int b    = rest / NCH;
    int nb   = rest % NCH;
    it.mq  = mq;
    it.bn0 = b * NN + nb * KN;
    it.lg  = labels_gt[b * MQ + mq];
    const float4* gp = bbox_gt + b * MM + mq * 4;
    it.g0 = gp[0]; it.g1 = gp[1]; it.g2 = gp[2]; it.g3 = gp[3];
    it.p0 = bbox_pred[it.bn0];
    it.p1 = bbox_pred[it.bn0 + 1];
}

__device__ __forceinline__ void load_s2(Item& it,
    const float* __restrict__ labels_pred)
{
    int lbl[4] = { it.lg.x, it.lg.y, it.lg.z, it.lg.w };
    const float* r0 = labels_pred + (size_t)it.bn0 * NC1;
#pragma unroll
    for (int j = 0; j < 4; ++j) {
        it.cls[0][j] = r0[lbl[j]];
        it.cls[1][j] = r0[NC1 + lbl[j]];
    }
}

__device__ __forceinline__ void compute_store(const Item& it,
    float4* __restrict__ out)
{
    const float4 g4[4] = { it.g0, it.g1, it.g2, it.g3 };
    const float4 p4[KN] = { it.p0, it.p1 };

    // p-state
    float pux[KN], puy[KN], pdx1[KN], pdy1[KN], pz1[KN], pw1[KN], parea[KN];
#pragma unroll
    for (int k = 0; k < KN; ++k) {
        float4 p = p4[k];
        pux[k]  = p.x - 0.5f * p.z;  puy[k]  = p.y - 0.5f * p.w;
        pdx1[k] = p.x + 0.5f * p.z + 1.0f;
        pdy1[k] = p.y + 0.5f * p.w + 1.0f;
        pz1[k]  = p.z + 1.0f;        pw1[k]  = p.w + 1.0f;
        parea[k] = pz1[k] * pw1[k];
    }

    float res[KN][4];
#pragma unroll
    for (int j = 0; j < 4; ++j) {
        float4 g = g4[j];
        float gux  = g.x - 0.5f * g.z,  guy = g.y - 0.5f * g.w;
        float gdx1 = g.x + 0.5f * g.z + 1.0f;
        float gdy1 = g.y + 0.5f * g.w + 1.0f;
        float gz1  = g.z + 1.0f,        gw1 = g.w + 1.0f;
        float ga   = gz1 * gw1;

#pragma unroll
        for (int k = 0; k < KN; ++k) {
            float iwrx = fminf(pdx1[k], gdx1) - fmaxf(pux[k], gux);
            float iwry = fminf(pdy1[k], gdy1) - fmaxf(puy[k], guy);
            float inter = fmaxf(iwrx, 0.0f) * fmaxf(iwry, 0.0f);

            float bwx = (pz1[k] + gz1) - iwrx;     // bound-from-sum identity
            float bwy = (pw1[k] + gw1) - iwry;

            float uni = (parea[k] + ga) - inter;
            float iou = inter * __builtin_amdgcn_rcpf(uni);
            float tt  = uni   * __builtin_amdgcn_rcpf(bwx * bwy);

            float4 p = p4[k];
            float bbox = fabsf(p.x - g.x) + fabsf(p.y - g.y)
                       + fabsf(p.z - g.z) + fabsf(p.w - g.w);

            res[k][j] = bbox + (1.0f - it.cls[k][j]) - tt - iou;
        }
    }

    if (it.valid) {
#pragma unroll
        for (int k = 0; k < KN; ++k)
            out[(size_t)(it.bn0 + k) * MQ + it.mq] =
                make_float4(res[k][0], res[k][1], res[k][2], res[k][3]);
    }
}

__global__ __launch_bounds__(BD) void cost_kernel(
    const float4* __restrict__ bbox_pred,
    const float*  __restrict__ labels_pred,
    const float4* __restrict__ bbox_gt,
    const int4*   __restrict__ labels_gt,
    float4*       __restrict__ out)
{
    const int tid = blockIdx.x * BD + threadIdx.x;

    Item A, B;
    // Prologue: stage-1 of items 0 and 1 in flight, then gathers for item 0
    load_s1(A, tid,          bbox_pred, bbox_gt, labels_gt);
    load_s1(B, tid + STRIDE, bbox_pred, bbox_gt, labels_gt);
    load_s2(A, labels_pred);          // one exposed lg->gather stall per thread

#pragma unroll
    for (int s = 0; s < ITEMS; s += 2) {
        compute_store(A, out);        // covers lg/g/p of B + clsA tail
        load_s2(B, labels_pred);      // lgB long since arrived
        if (s + 2 < ITEMS)
            load_s1(A, tid + (s + 2) * STRIDE, bbox_pred, bbox_gt, labels_gt);
        compute_store(B, out);        // covers clsB + stage-1 of new A
        if (s + 3 < ITEMS)
            load_s1(B, tid + (s + 3) * STRIDE, bbox_pred, bbox_gt, labels_gt);
        if (s + 2 < ITEMS)
            load_s2(A, labels_pred);  // lgA arrived during compute B
    }
}

extern "C" void kernel_launch(void* const* d_in, const int* in_sizes, int n_in,
                              void* d_out, int out_size, void* d_ws, size_t ws_size,
                              hipStream_t stream) {
    const float4* bbox_pred   = (const float4*)d_in[0];
    const float*  labels_pred = (const float*) d_in[1];
    const float4* bbox_gt     = (const float4*)d_in[2];
    const int4*   labels_gt   = (const int4*)  d_in[3];
    float4*       out         = (float4*)d_out;

    cost_kernel<<<GRID, BD, 0, stream>>>(bbox_pred, labels_pred, bbox_gt,
                                         labels_gt, out);
}

// Round 10
// 29.115 us; speedup vs baseline: 1.3141x; 1.2192x over previous
//
#include <hip/hip_runtime.h>

// Problem constants (match reference).
#define BB    64
#define NN    900
#define MM    300
#define NC1   92
#define MQ    75                 // m-groups of 4
#define KN    4                  // n-rows per item
#define NCH   (NN / KN)          // 225
#define HB    (BB / 2)           // 32 — b-split pipeline depth 2
#define TOTAL (HB * NCH * MQ)    // 540,000 threads
#define BD    256

// Item-B global-address deltas (in elements of the respective types)
#define D_LG  (HB * MQ)          // int4 elements
#define D_G   (HB * MM)          // float4 elements
#define D_P   (HB * NN)          // float4 elements
#define D_LP  ((size_t)HB * NN * NC1)  // floats
#define D_OUT ((size_t)HB * NN * MQ)   // float4 elements

__device__ __forceinline__ void compute_store(
    const float4 p4[KN], const float4 g4[4], const float cls[KN][4],
    int bn0, int mq, float4* __restrict__ out)
{
    float pux[KN], puy[KN], pdx1[KN], pdy1[KN], pz1[KN], pw1[KN], parea[KN];
#pragma unroll
    for (int k = 0; k < KN; ++k) {
        float4 p = p4[k];
        pux[k]  = p.x - 0.5f * p.z;  puy[k]  = p.y - 0.5f * p.w;
        pdx1[k] = p.x + 0.5f * p.z + 1.0f;
        pdy1[k] = p.y + 0.5f * p.w + 1.0f;
        pz1[k]  = p.z + 1.0f;        pw1[k]  = p.w + 1.0f;
        parea[k] = pz1[k] * pw1[k];
    }

    float res[KN][4];
#pragma unroll
    for (int j = 0; j < 4; ++j) {
        float4 g = g4[j];
        float gux  = g.x - 0.5f * g.z,  guy = g.y - 0.5f * g.w;
        float gdx1 = g.x + 0.5f * g.z + 1.0f;
        float gdy1 = g.y + 0.5f * g.w + 1.0f;
        float gz1  = g.z + 1.0f,        gw1 = g.w + 1.0f;
        float ga   = gz1 * gw1;

#pragma unroll
        for (int k = 0; k < KN; ++k) {
            float iwrx = fminf(pdx1[k], gdx1) - fmaxf(pux[k], gux);
            float iwry = fminf(pdy1[k], gdy1) - fmaxf(puy[k], guy);
            float inter = fmaxf(iwrx, 0.0f) * fmaxf(iwry, 0.0f);

            float bwx = (pz1[k] + gz1) - iwrx;   // bound-from-sum identity
            float bwy = (pw1[k] + gw1) - iwry;

            float uni = (parea[k] + ga) - inter;
            float iou = inter * __builtin_amdgcn_rcpf(uni);
            float tt  = uni   * __builtin_amdgcn_rcpf(bwx * bwy);

            float4 p = p4[k];
            float bbox = fabsf(p.x - g.x) + fabsf(p.y - g.y)
                       + fabsf(p.z - g.z) + fabsf(p.w - g.w);

            res[k][j] = bbox + (1.0f - cls[k][j]) - tt - iou;
        }
    }

#pragma unroll
    for (int k = 0; k < KN; ++k)
        out[(size_t)(bn0 + k) * MQ + mq] =
            make_float4(res[k][0], res[k][1], res[k][2], res[k][3]);
}

__global__ __launch_bounds__(BD, 4) void cost_kernel(
    const float4* __restrict__ bbox_pred,   // [B*N]
    const float*  __restrict__ labels_pred, // [B*N*92]
    const float4* __restrict__ bbox_gt,     // [B*M]
    const int4*   __restrict__ labels_gt,   // [B*M/4]
    float4*       __restrict__ out)         // [B*N*MQ]
{
    int i = blockIdx.x * BD + threadIdx.x;
    if (i >= TOTAL) return;

    int mq   = i % MQ;
    int rest = i / MQ;
    int b    = rest / NCH;      // 0..31  (item A); item B = b+32
    int nb   = rest % NCH;
    int bn0  = b * NN + nb * KN;

    // ---- Stage-1 loads, both items (all independent) ----
    int4 lgA = labels_gt[b * MQ + mq];
    int4 lgB = labels_gt[b * MQ + mq + D_LG];

    float4 gA[4], gB[4];
    const float4* gp = bbox_gt + b * MM + mq * 4;
#pragma unroll
    for (int j = 0; j < 4; ++j) { gA[j] = gp[j]; gB[j] = gp[j + D_G]; }

    float4 pA[KN], pB[KN];
    const float4* pp = bbox_pred + bn0;
#pragma unroll
    for (int k = 0; k < KN; ++k) { pA[k] = pp[k]; pB[k] = pp[k + D_P]; }

    // ---- Item-A gathers (lgA latency was covered by B's stage-1 issues) ----
    const float* lpA = labels_pred + (size_t)bn0 * NC1;
    int lblA[4] = { lgA.x, lgA.y, lgA.z, lgA.w };
    float clsA[KN][4];
#pragma unroll
    for (int k = 0; k < KN; ++k)
#pragma unroll
        for (int j = 0; j < 4; ++j)
            clsA[k][j] = lpA[(size_t)k * NC1 + lblA[j]];

    // ---- Compute/store A (covers gather-A tail + nothing depends on B yet) ----
    compute_store(pA, gA, clsA, bn0, mq, out);

    // ---- Item-B gathers (lgB arrived ~a full compute phase ago) ----
    const float* lpB = lpA + D_LP;
    int lblB[4] = { lgB.x, lgB.y, lgB.z, lgB.w };
    float clsB[KN][4];
#pragma unroll
    for (int k = 0; k < KN; ++k)
#pragma unroll
        for (int j = 0; j < 4; ++j)
            clsB[k][j] = lpB[(size_t)k * NC1 + lblB[j]];

    compute_store(pB, gB, clsB, bn0, mq, out + D_OUT);
}

extern "C" void kernel_launch(void* const* d_in, const int* in_sizes, int n_in,
                              void* d_out, int out_size, void* d_ws, size_t ws_size,
                              hipStream_t stream) {
    const float4* bbox_pred   = (const float4*)d_in[0];
    const float*  labels_pred = (const float*) d_in[1];
    const float4* bbox_gt     = (const float4*)d_in[2];
    const int4*   labels_gt   = (const int4*)  d_in[3];
    float4*       out         = (float4*)d_out;

    const int grid = (TOTAL + BD - 1) / BD;   // 2110 blocks = 8440 waves
    cost_kernel<<<grid, BD, 0, stream>>>(bbox_pred, labels_pred, bbox_gt,
                                         labels_gt, out);
}

// Round 11
// 27.241 us; speedup vs baseline: 1.4045x; 1.0688x over previous
//
#include <hip/hip_runtime.h>

// Problem constants (match reference).
#define BB   64
#define NN   900
#define MM   300
#define NC1  92          // NUM_CLASSES + 1
#define MQ   75          // float4 groups per m-row (300/4)
#define KN   4           // n-rows per thread
#define NCH  (NN / KN)   // 225

typedef float f32x2 __attribute__((ext_vector_type(2)));

static __device__ __forceinline__ f32x2 min2(f32x2 a, f32x2 b) {
    return f32x2{ fminf(a.x, b.x), fminf(a.y, b.y) };
}
static __device__ __forceinline__ f32x2 max2(f32x2 a, f32x2 b) {
    return f32x2{ fmaxf(a.x, b.x), fmaxf(a.y, b.y) };
}

__global__ __launch_bounds__(256) void cost_kernel(
    const float4* __restrict__ bbox_pred,   // [B*N] (cx,cy,w,h)
    const float*  __restrict__ labels_pred, // [B*N*92]
    const float4* __restrict__ bbox_gt,     // [B*M]
    const int4*   __restrict__ labels_gt,   // [B*M/4]
    float4*       __restrict__ out)         // [B*N*MQ]
{
    const int total = BB * NCH * MQ;        // 1,080,000
    int idx = blockIdx.x * blockDim.x + threadIdx.x;
    if (idx >= total) return;

    int mq   = idx % MQ;
    int rest = idx / MQ;
    int b    = rest / NCH;
    int nb   = rest % NCH;
    int bn0  = b * NN + nb * KN;

    // ---------- Phase 1: issue all loads up front ----------
    int4 lg = labels_gt[b * MQ + mq];

    float4 g4[4];
#pragma unroll
    for (int j = 0; j < 4; ++j)
        g4[j] = bbox_gt[b * MM + mq * 4 + j];

    float4 p4[KN];
#pragma unroll
    for (int k = 0; k < KN; ++k)
        p4[k] = bbox_pred[bn0 + k];

    int lbl[4] = { lg.x, lg.y, lg.z, lg.w };
    float cls1[KN][4];                       // 1 - cls, folded here
#pragma unroll
    for (int k = 0; k < KN; ++k) {
        const float* lp = labels_pred + (size_t)(bn0 + k) * NC1;
#pragma unroll
        for (int j = 0; j < 4; ++j)
            cls1[k][j] = 1.0f - lp[lbl[j]];
    }

    // ---------- Phase 2: gt state (packed) ----------
    f32x2 gc[4], gs[4], gu[4], gd1[4], gs1[4];
    float ga[4];
#pragma unroll
    for (int j = 0; j < 4; ++j) {
        float4 g = g4[j];
        gc[j]  = f32x2{ g.x, g.y };
        gs[j]  = f32x2{ g.z, g.w };
        gu[j]  = gc[j] - 0.5f * gs[j];       // pk_fma
        gs1[j] = gs[j] + 1.0f;               // pk_add
        gd1[j] = gu[j] + gs1[j];             // pk_add  (= dr + 1)
        ga[j]  = gs1[j].x * gs1[j].y;
    }

    // ---------- Phase 3: compute + store ----------
#pragma unroll
    for (int k = 0; k < KN; ++k) {
        float4 p = p4[k];
        f32x2 pc  = f32x2{ p.x, p.y };
        f32x2 ps  = f32x2{ p.z, p.w };
        f32x2 pu  = pc - 0.5f * ps;          // pk_fma
        f32x2 ps1 = ps + 1.0f;               // pk_add
        f32x2 pd1 = pu + ps1;                // pk_add
        float parea = ps1.x * ps1.y;

        float res[4];
#pragma unroll
        for (int j = 0; j < 4; ++j) {
            f32x2 iwr = min2(pd1, gd1[j]) - max2(pu, gu[j]);
            f32x2 iw  = max2(iwr, f32x2{ 0.0f, 0.0f });
            float inter = iw.x * iw.y;

            // bound via sum identity: iwr + bw = ps1 + gs1
            f32x2 bw = (ps1 + gs1[j]) - iwr;
            float barea = bw.x * bw.y;

            float uni   = (parea + ga[j]) - inter;
            // iou + bg-term combined: inter/uni + uni/barea with ONE rcp
            float denom = uni * barea;
            float num   = inter * barea + uni * uni;
            float frac  = num * __builtin_amdgcn_rcpf(denom);

            f32x2 d1 = pc - gc[j];           // pk_sub
            f32x2 d2 = ps - gs[j];           // pk_sub
            float bbox = (fabsf(d1.x) + fabsf(d1.y))
                       + (fabsf(d2.x) + fabsf(d2.y));   // abs = free modifiers

            res[j] = (bbox + cls1[k][j]) - frac;
        }

        out[(size_t)(bn0 + k) * MQ + mq] =
            make_float4(res[0], res[1], res[2], res[3]);
    }
}

extern "C" void kernel_launch(void* const* d_in, const int* in_sizes, int n_in,
                              void* d_out, int out_size, void* d_ws, size_t ws_size,
                              hipStream_t stream) {
    const float4* bbox_pred   = (const float4*)d_in[0];
    const float*  labels_pred = (const float*) d_in[1];
    const float4* bbox_gt     = (const float4*)d_in[2];
    const int4*   labels_gt   = (const int4*)  d_in[3];
    float4*       out         = (float4*)d_out;

    const int total = BB * NCH * MQ;
    const int block = 256;
    const int grid  = (total + block - 1) / block;   // 4219 blocks
    cost_kernel<<<grid, block, 0, stream>>>(bbox_pred, labels_pred, bbox_gt,
                                            labels_gt, out);
}